// Round 1
// baseline (1318.310 us; speedup 1.0000x reference)
//
#include <hip/hip_runtime.h>
#include <hip/hip_bf16.h>
#include <math.h>

#define HIDDEN 512
#define NHEADS 8
#define HDIM 64
#define SLEN 2048
#define BATCH 4
#define NROWS (BATCH*SLEN)   /* 8192 */
#define NBUCKETS 32
#define RTAB (2*SLEN-1)      /* 4095 */

// ---------------------------------------------------------------------------
// Kernel 1: precompute relative-position bias as biasrel[h][rel + SLEN-1],
// rel = t - s in [-(S-1), S-1]. Matches reference bucket math exactly.
// ---------------------------------------------------------------------------
__global__ __launch_bounds__(256) void bias_precompute(
    const float* __restrict__ bias_table, float* __restrict__ biasrel) {
  int i = blockIdx.x * 256 + threadIdx.x;
  if (i >= NHEADS * RTAB) return;
  int h = i / RTAB;
  int idx = i - h * RTAB;
  int rel = idx - (SLEN - 1);
  int ret = rel > 0 ? 16 : 0;          // bidirectional: nb=16 after halving
  int a = rel < 0 ? -rel : rel;
  int bidx;
  if (a < 8) {
    bidx = a;                          // max_exact = 8
  } else {
    // val_if_large = 8 + int(log(a/8)/log(16) * 8), clamped to 15
    float val = logf((float)a * 0.125f) / logf(16.0f) * 8.0f;
    bidx = 8 + (int)val;
    if (bidx > 15) bidx = 15;
  }
  biasrel[i] = bias_table[(ret + bidx) * NHEADS + h];
}

// ---------------------------------------------------------------------------
// Kernel 2: f32 GEMM, C[M=8192, N=512] = A @ W, 64x64 tile, 4x4 micro-tile.
// qkv_layout=1 stores to [B,H,S,D] (head = blockIdx.y), else row-major.
// ---------------------------------------------------------------------------
__global__ __launch_bounds__(256) void gemm64(
    const float* __restrict__ A, const float* __restrict__ W,
    float* __restrict__ O, int qkv_layout) {
  __shared__ float As[16][68];   // [k][m], padded
  __shared__ float Bs[16][68];   // [k][n], padded
  int tid = threadIdx.x;
  int tx = tid & 15, ty = tid >> 4;
  int m0 = blockIdx.x << 6, n0 = blockIdx.y << 6;
  float c[4][4];
#pragma unroll
  for (int i = 0; i < 4; ++i)
#pragma unroll
    for (int j = 0; j < 4; ++j) c[i][j] = 0.f;

  for (int k0 = 0; k0 < HIDDEN; k0 += 16) {
    __syncthreads();
#pragma unroll
    for (int e = 0; e < 4; ++e) {
      int flat = tid + (e << 8);
      int ka = flat & 15, row = flat >> 4;
      As[ka][row] = A[(size_t)(m0 + row) * HIDDEN + k0 + ka];
      int col = flat & 63, kb = flat >> 6;
      Bs[kb][col] = W[(size_t)(k0 + kb) * HIDDEN + n0 + col];
    }
    __syncthreads();
#pragma unroll
    for (int kk = 0; kk < 16; ++kk) {
      float4 a4 = *(const float4*)&As[kk][ty << 2];
      float4 b4 = *(const float4*)&Bs[kk][tx << 2];
      float av[4] = {a4.x, a4.y, a4.z, a4.w};
      float bv[4] = {b4.x, b4.y, b4.z, b4.w};
#pragma unroll
      for (int i = 0; i < 4; ++i)
#pragma unroll
        for (int j = 0; j < 4; ++j) c[i][j] += av[i] * bv[j];
    }
  }

  if (qkv_layout) {
    // head h == blockIdx.y (HIDDEN/64 == NHEADS), d = tx*4..+3
#pragma unroll
    for (int i = 0; i < 4; ++i) {
      int m = m0 + (ty << 2) + i;
      int b = m >> 11, s = m & (SLEN - 1);
      float4 val = make_float4(c[i][0], c[i][1], c[i][2], c[i][3]);
      *(float4*)&O[(((size_t)b * NHEADS + blockIdx.y) * SLEN + s) * HDIM + (tx << 2)] = val;
    }
  } else {
#pragma unroll
    for (int i = 0; i < 4; ++i) {
      int m = m0 + (ty << 2) + i;
      float4 val = make_float4(c[i][0], c[i][1], c[i][2], c[i][3]);
      *(float4*)&O[(size_t)m * HIDDEN + n0 + (tx << 2)] = val;
    }
  }
}

// ---------------------------------------------------------------------------
// Kernel 3: flash attention. Block = 256 threads = one (b*h, 64-row q-tile).
// Lane (r = tid>>2, qd = tid&3): owns q-row r; score cols c = qd+4j; out
// d-slice [16*qd, 16*qd+16). Online softmax state per row, replicated over
// the 4 lanes of the row (shfl_xor(1), shfl_xor(2) reductions).
// ---------------------------------------------------------------------------
__global__ __launch_bounds__(256) void flash_attn(
    const float* __restrict__ q, const float* __restrict__ k,
    const float* __restrict__ v, const float* __restrict__ biasrel,
    float* __restrict__ attn_out) {
  __shared__ float qs[64][68];
  __shared__ float ks[64][68];
  __shared__ float vs[64][64];
  int tid = threadIdx.x;
  int bh = blockIdx.y;
  int h = bh & (NHEADS - 1), b = bh >> 3;
  int q0 = blockIdx.x << 6;
  int r = tid >> 2, qd = tid & 3;
  const float* qp = q + (size_t)bh * SLEN * HDIM;
  const float* kp = k + (size_t)bh * SLEN * HDIM;
  const float* vp = v + (size_t)bh * SLEN * HDIM;

  // load Q tile (64x64)
#pragma unroll
  for (int e = 0; e < 4; ++e) {
    int flat = tid + (e << 8);
    int row = flat >> 4, c4 = (flat & 15) << 2;
    *(float4*)&qs[row][c4] = *(const float4*)(qp + (size_t)(q0 + row) * HDIM + c4);
  }

  float m_run = -INFINITY, l_run = 0.f;
  float acc[16];
#pragma unroll
  for (int i = 0; i < 16; ++i) acc[i] = 0.f;
  const float* brh = biasrel + h * RTAB + (SLEN - 1) - (q0 + r);

  for (int t0 = 0; t0 < SLEN; t0 += 64) {
    __syncthreads();
#pragma unroll
    for (int e = 0; e < 4; ++e) {
      int flat = tid + (e << 8);
      int row = flat >> 4, c4 = (flat & 15) << 2;
      *(float4*)&ks[row][c4] = *(const float4*)(kp + (size_t)(t0 + row) * HDIM + c4);
      *(float4*)&vs[row][c4] = *(const float4*)(vp + (size_t)(t0 + row) * HDIM + c4);
    }
    __syncthreads();

    // scores: sc[j] = q[r] . k[qd+4j]
    float sc[16];
#pragma unroll
    for (int j = 0; j < 16; ++j) sc[j] = 0.f;
#pragma unroll
    for (int x4 = 0; x4 < 16; ++x4) {
      float4 a = *(const float4*)&qs[r][x4 << 2];
#pragma unroll
      for (int j = 0; j < 16; ++j) {
        float4 bb = *(const float4*)&ks[qd + (j << 2)][x4 << 2];
        sc[j] += a.x * bb.x + a.y * bb.y + a.z * bb.z + a.w * bb.w;
      }
    }

    float mloc = -INFINITY;
#pragma unroll
    for (int j = 0; j < 16; ++j) {
      sc[j] = sc[j] * 0.125f + brh[t0 + qd + (j << 2)];
      mloc = fmaxf(mloc, sc[j]);
    }
    mloc = fmaxf(mloc, __shfl_xor(mloc, 1, 64));
    mloc = fmaxf(mloc, __shfl_xor(mloc, 2, 64));
    float m_new = fmaxf(m_run, mloc);
    float alpha = __expf(m_run - m_new);   // first tile: exp(-inf)=0
    float rsum = 0.f;
    float pexp[16];
#pragma unroll
    for (int j = 0; j < 16; ++j) {
      pexp[j] = __expf(sc[j] - m_new);
      rsum += pexp[j];
    }
    rsum += __shfl_xor(rsum, 1, 64);
    rsum += __shfl_xor(rsum, 2, 64);
    l_run = l_run * alpha + rsum;
    m_run = m_new;
#pragma unroll
    for (int i = 0; i < 16; ++i) acc[i] *= alpha;

    // PV: acc[d] += sum_c p[r][c] * v[c][d], p shared across 4 lanes via shfl
#pragma unroll
    for (int j = 0; j < 16; ++j) {
      float pj = pexp[j];
#pragma unroll
      for (int sx = 0; sx < 4; ++sx) {
        float p = __shfl_xor(pj, sx, 64);
        int c = (qd ^ sx) + (j << 2);
        const float* vr = &vs[c][qd << 4];
#pragma unroll
        for (int i4 = 0; i4 < 4; ++i4) {
          float4 vvv = *(const float4*)(vr + (i4 << 2));
          acc[i4 * 4 + 0] += p * vvv.x;
          acc[i4 * 4 + 1] += p * vvv.y;
          acc[i4 * 4 + 2] += p * vvv.z;
          acc[i4 * 4 + 3] += p * vvv.w;
        }
      }
    }
  }

  float inv = 1.f / l_run;
  float* op = attn_out + ((size_t)b * SLEN + q0 + r) * HIDDEN + h * HDIM + (qd << 4);
#pragma unroll
  for (int i4 = 0; i4 < 4; ++i4) {
    float4 val = make_float4(acc[i4 * 4 + 0] * inv, acc[i4 * 4 + 1] * inv,
                             acc[i4 * 4 + 2] * inv, acc[i4 * 4 + 3] * inv);
    *(float4*)&op[i4 << 2] = val;
  }
}

// ---------------------------------------------------------------------------
extern "C" void kernel_launch(void* const* d_in, const int* in_sizes, int n_in,
                              void* d_out, int out_size, void* d_ws, size_t ws_size,
                              hipStream_t stream) {
  const float* x          = (const float*)d_in[0];
  const float* Wq         = (const float*)d_in[1];
  const float* Wk         = (const float*)d_in[2];
  const float* Wv         = (const float*)d_in[3];
  const float* Wo         = (const float*)d_in[4];
  const float* bias_table = (const float*)d_in[5];
  float* out = (float*)d_out;

  float* ws      = (float*)d_ws;
  float* q_ws    = ws;                      // 8192*512
  float* k_ws    = ws + (size_t)NROWS * HIDDEN;
  float* v_ws    = ws + (size_t)2 * NROWS * HIDDEN;
  float* attno   = ws + (size_t)3 * NROWS * HIDDEN;
  float* biasrel = ws + (size_t)4 * NROWS * HIDDEN;  // 8*4095 floats

  bias_precompute<<<(NHEADS * RTAB + 255) / 256, 256, 0, stream>>>(bias_table, biasrel);

  dim3 gg(NROWS / 64, HIDDEN / 64);  // (128, 8)
  gemm64<<<gg, 256, 0, stream>>>(x, Wq, q_ws, 1);
  gemm64<<<gg, 256, 0, stream>>>(x, Wk, k_ws, 1);
  gemm64<<<gg, 256, 0, stream>>>(x, Wv, v_ws, 1);

  flash_attn<<<dim3(SLEN / 64, BATCH * NHEADS), 256, 0, stream>>>(
      q_ws, k_ws, v_ws, biasrel, attno);

  gemm64<<<gg, 256, 0, stream>>>(attno, Wo, out, 0);
}

// Round 2
// 392.353 us; speedup vs baseline: 3.3600x; 3.3600x over previous
//
#include <hip/hip_runtime.h>
#include <hip/hip_bf16.h>
#include <math.h>

#define HIDDEN 512
#define NHEADS 8
#define HDIM 64
#define SLEN 2048
#define BATCH 4
#define NROWS (BATCH*SLEN)   /* 8192 */
#define RTAB (2*SLEN-1)      /* 4095 */

typedef _Float16 f16x8 __attribute__((ext_vector_type(8)));
typedef float f32x4 __attribute__((ext_vector_type(4)));
typedef unsigned short u16;
typedef u16 u16x8 __attribute__((ext_vector_type(8)));

// ---------------------------------------------------------------------------
// Kernel 1: precompute relative-position bias biasrel[h][t-s+2047].
// ---------------------------------------------------------------------------
__global__ __launch_bounds__(256) void bias_precompute(
    const float* __restrict__ bias_table, float* __restrict__ biasrel) {
  int i = blockIdx.x * 256 + threadIdx.x;
  if (i >= NHEADS * RTAB) return;
  int h = i / RTAB;
  int idx = i - h * RTAB;
  int rel = idx - (SLEN - 1);
  int ret = rel > 0 ? 16 : 0;
  int a = rel < 0 ? -rel : rel;
  int bidx;
  if (a < 8) {
    bidx = a;
  } else {
    float val = logf((float)a * 0.125f) / logf(16.0f) * 8.0f;
    bidx = 8 + (int)val;
    if (bidx > 15) bidx = 15;
  }
  biasrel[i] = bias_table[(ret + bidx) * NHEADS + h];
}

// ---------------------------------------------------------------------------
// Kernel 2: f32 GEMM C[8192,512] = A @ W; 64x64 tile, 4x4 micro-tile.
// qkv_layout=1: store f16 (u16 bits) to [B,H,S,D]; else f32 row-major.
// ---------------------------------------------------------------------------
__global__ __launch_bounds__(256) void gemm64(
    const float* __restrict__ A, const float* __restrict__ W,
    void* __restrict__ O, int qkv_layout) {
  __shared__ float As[16][68];
  __shared__ float Bs[16][68];
  int tid = threadIdx.x;
  int tx = tid & 15, ty = tid >> 4;
  int m0 = blockIdx.x << 6, n0 = blockIdx.y << 6;
  float c[4][4];
#pragma unroll
  for (int i = 0; i < 4; ++i)
#pragma unroll
    for (int j = 0; j < 4; ++j) c[i][j] = 0.f;

  for (int k0 = 0; k0 < HIDDEN; k0 += 16) {
    __syncthreads();
#pragma unroll
    for (int e = 0; e < 4; ++e) {
      int flat = tid + (e << 8);
      int ka = flat & 15, row = flat >> 4;
      As[ka][row] = A[(size_t)(m0 + row) * HIDDEN + k0 + ka];
      int col = flat & 63, kb = flat >> 6;
      Bs[kb][col] = W[(size_t)(k0 + kb) * HIDDEN + n0 + col];
    }
    __syncthreads();
#pragma unroll
    for (int kk = 0; kk < 16; ++kk) {
      float4 a4 = *(const float4*)&As[kk][ty << 2];
      float4 b4 = *(const float4*)&Bs[kk][tx << 2];
      float av[4] = {a4.x, a4.y, a4.z, a4.w};
      float bv[4] = {b4.x, b4.y, b4.z, b4.w};
#pragma unroll
      for (int i = 0; i < 4; ++i)
#pragma unroll
        for (int j = 0; j < 4; ++j) c[i][j] += av[i] * bv[j];
    }
  }

  if (qkv_layout) {
    u16* O16 = (u16*)O;
#pragma unroll
    for (int i = 0; i < 4; ++i) {
      int m = m0 + (ty << 2) + i;
      int b = m >> 11, s = m & (SLEN - 1);
      ushort4 pk;
      _Float16 h0 = (_Float16)c[i][0]; pk.x = *(u16*)&h0;
      _Float16 h1 = (_Float16)c[i][1]; pk.y = *(u16*)&h1;
      _Float16 h2 = (_Float16)c[i][2]; pk.z = *(u16*)&h2;
      _Float16 h3 = (_Float16)c[i][3]; pk.w = *(u16*)&h3;
      *(ushort4*)&O16[(((size_t)b * NHEADS + blockIdx.y) * SLEN + s) * HDIM + (tx << 2)] = pk;
    }
  } else {
    float* Of = (float*)O;
#pragma unroll
    for (int i = 0; i < 4; ++i) {
      int m = m0 + (ty << 2) + i;
      float4 val = make_float4(c[i][0], c[i][1], c[i][2], c[i][3]);
      *(float4*)&Of[(size_t)m * HIDDEN + n0 + (tx << 2)] = val;
    }
  }
}

// ---------------------------------------------------------------------------
// Kernel 3: MFMA flash attention. 256 thr = 4 waves; block = 64 q-rows
// (16/wave), KVBLK = 64. f16 MFMA 16x16x32. C/D layout (m89):
// col = lane&15, row = (lane>>4)*4 + reg.
// ---------------------------------------------------------------------------
__global__ __launch_bounds__(256) void flash_attn_mfma(
    const u16* __restrict__ qg, const u16* __restrict__ kg,
    const u16* __restrict__ vg, const float* __restrict__ biasrel,
    float* __restrict__ attn_out) {
  __shared__ u16 Ks[64][72];       // [kv][d], pad -> 2-way (free)
  __shared__ u16 Vt[64][72];       // [d][kv] transposed
  __shared__ u16 Pb[4][16][72];    // per-wave P tile [qrow][kv]

  const int tid = threadIdx.x;
  const int w = tid >> 6, l = tid & 63;
  const int lr = l & 15, lg = l >> 4;

  // XCD swizzle: xcd = bid%8 gets bh in [4*xcd, 4*xcd+4) -> K/V L2-resident
  int bid = blockIdx.x;
  int xcd = bid & 7, idx = bid >> 3;
  int bh = (xcd << 2) + (idx >> 5);
  int bx = idx & 31;
  int h = bh & 7, b = bh >> 3;
  int q0 = bx << 6;

  const u16* qp = qg + (size_t)bh * (SLEN * HDIM);
  const u16* kp = kg + (size_t)bh * (SLEN * HDIM);
  const u16* vp = vg + (size_t)bh * (SLEN * HDIM);

  // Q A-frags in registers: A[r=lr][k = kk*32 + lg*8 + j]
  const u16* qrow = qp + (size_t)(q0 + (w << 4) + lr) * HDIM + (lg << 3);
  f16x8 aq0 = *(const f16x8*)(qrow);
  f16x8 aq1 = *(const f16x8*)(qrow + 32);

  // bias base: bias[ct][reg] at tile t0 = bb[t0 + 16*ct - reg]
  const float* bb = biasrel + h * RTAB + (SLEN - 1) + lr - (q0 + (w << 4) + (lg << 2));

  f32x4 acc[4] = {};               // 4 d-tiles of O
  float m_run[4], l_run[4];
#pragma unroll
  for (int r = 0; r < 4; ++r) { m_run[r] = -3.0e38f; l_run[r] = 0.f; }

  for (int t0 = 0; t0 < SLEN; t0 += 64) {
    // prefetch bias (independent of staging/MFMA)
    float bias[4][4];
#pragma unroll
    for (int ct = 0; ct < 4; ++ct)
#pragma unroll
      for (int r = 0; r < 4; ++r) bias[ct][r] = bb[t0 + (ct << 4) - r];

    __syncthreads();
    // stage K row-major (coalesced 16B chunks)
#pragma unroll
    for (int e = 0; e < 2; ++e) {
      int c = tid + (e << 8);
      int row = c >> 3, c8 = c & 7;
      *(float4*)&Ks[row][c8 << 3] = *(const float4*)(kp + (size_t)(t0 + row) * HDIM + (c8 << 3));
    }
    // stage V transposed: Vt[d][kv]
#pragma unroll
    for (int e = 0; e < 2; ++e) {
      int c = tid + (e << 8);
      int kr = c & 63, d0 = (c >> 6) << 3;
      u16x8 vv = *(const u16x8*)(vp + (size_t)(t0 + kr) * HDIM + d0);
#pragma unroll
      for (int j = 0; j < 8; ++j) Vt[d0 + j][kr] = vv[j];
    }
    __syncthreads();

    // S = Q K^T : B-frag B[k=d][c=kv] = Ks[ct*16+lr][kk*32+lg*8..+7]
    f32x4 sc[4] = {};
#pragma unroll
    for (int ct = 0; ct < 4; ++ct) {
      sc[ct] = __builtin_amdgcn_mfma_f32_16x16x32_f16(
          aq0, *(const f16x8*)&Ks[(ct << 4) + lr][lg << 3], sc[ct], 0, 0, 0);
      sc[ct] = __builtin_amdgcn_mfma_f32_16x16x32_f16(
          aq1, *(const f16x8*)&Ks[(ct << 4) + lr][32 + (lg << 3)], sc[ct], 0, 0, 0);
    }

    // online softmax per owned row (reg r); row spread over 16-lane group
    float alpha[4];
#pragma unroll
    for (int r = 0; r < 4; ++r) {
      float mx = -3.0e38f;
#pragma unroll
      for (int ct = 0; ct < 4; ++ct) {
        float sv = sc[ct][r] * 0.125f + bias[ct][r];
        sc[ct][r] = sv;
        mx = fmaxf(mx, sv);
      }
      mx = fmaxf(mx, __shfl_xor(mx, 1, 64));
      mx = fmaxf(mx, __shfl_xor(mx, 2, 64));
      mx = fmaxf(mx, __shfl_xor(mx, 4, 64));
      mx = fmaxf(mx, __shfl_xor(mx, 8, 64));
      float mnew = fmaxf(m_run[r], mx);
      alpha[r] = __expf(m_run[r] - mnew);
      m_run[r] = mnew;
      float rs = 0.f;
#pragma unroll
      for (int ct = 0; ct < 4; ++ct) {
        float pe = __expf(sc[ct][r] - mnew);
        sc[ct][r] = pe;
        rs += pe;
      }
      rs += __shfl_xor(rs, 1, 64);
      rs += __shfl_xor(rs, 2, 64);
      rs += __shfl_xor(rs, 4, 64);
      rs += __shfl_xor(rs, 8, 64);
      l_run[r] = l_run[r] * alpha[r] + rs;
    }

    // P -> LDS (f16), per-wave buffer; same-wave LDS in-order => no barrier
#pragma unroll
    for (int ct = 0; ct < 4; ++ct)
#pragma unroll
      for (int r = 0; r < 4; ++r) {
        _Float16 hp = (_Float16)sc[ct][r];
        Pb[w][(lg << 2) + r][(ct << 4) + lr] = *(u16*)&hp;
      }

    // rescale O accumulators
#pragma unroll
    for (int dt = 0; dt < 4; ++dt)
#pragma unroll
      for (int r = 0; r < 4; ++r) acc[dt][r] *= alpha[r];

    // O += P V : A-frag = Pb[lr][kk*32+lg*8..], B-frag = Vt[dt*16+lr][kk*32+lg*8..]
    f16x8 pa0 = *(const f16x8*)&Pb[w][lr][lg << 3];
    f16x8 pa1 = *(const f16x8*)&Pb[w][lr][32 + (lg << 3)];
#pragma unroll
    for (int dt = 0; dt < 4; ++dt) {
      acc[dt] = __builtin_amdgcn_mfma_f32_16x16x32_f16(
          pa0, *(const f16x8*)&Vt[(dt << 4) + lr][lg << 3], acc[dt], 0, 0, 0);
      acc[dt] = __builtin_amdgcn_mfma_f32_16x16x32_f16(
          pa1, *(const f16x8*)&Vt[(dt << 4) + lr][32 + (lg << 3)], acc[dt], 0, 0, 0);
    }
  }

  // epilogue: O[row][d] / l ; row = 4*lg + r, d = 16*dt + lr
  float* op = attn_out + ((size_t)(b * SLEN) + q0 + (w << 4)) * HIDDEN + (h << 6);
#pragma unroll
  for (int r = 0; r < 4; ++r) {
    float inv = 1.f / l_run[r];
#pragma unroll
    for (int dt = 0; dt < 4; ++dt)
      op[(size_t)((lg << 2) + r) * HIDDEN + (dt << 4) + lr] = acc[dt][r] * inv;
  }
}

// ---------------------------------------------------------------------------
extern "C" void kernel_launch(void* const* d_in, const int* in_sizes, int n_in,
                              void* d_out, int out_size, void* d_ws, size_t ws_size,
                              hipStream_t stream) {
  const float* x          = (const float*)d_in[0];
  const float* Wq         = (const float*)d_in[1];
  const float* Wk         = (const float*)d_in[2];
  const float* Wv         = (const float*)d_in[3];
  const float* Wo         = (const float*)d_in[4];
  const float* bias_table = (const float*)d_in[5];
  float* out = (float*)d_out;

  u16* qb = (u16*)d_ws;                               // f16 [B,H,S,D] 8MB
  u16* kb = qb + (size_t)NROWS * HIDDEN;              // 8MB
  u16* vb = kb + (size_t)NROWS * HIDDEN;              // 8MB
  float* attno   = (float*)(vb + (size_t)NROWS * HIDDEN);   // f32 16MB
  float* biasrel = attno + (size_t)NROWS * HIDDEN;          // 8*4095 f32

  bias_precompute<<<(NHEADS * RTAB + 255) / 256, 256, 0, stream>>>(bias_table, biasrel);

  dim3 gg(NROWS / 64, HIDDEN / 64);
  gemm64<<<gg, 256, 0, stream>>>(x, Wq, qb, 1);
  gemm64<<<gg, 256, 0, stream>>>(x, Wk, kb, 1);
  gemm64<<<gg, 256, 0, stream>>>(x, Wv, vb, 1);

  flash_attn_mfma<<<SLEN / 64 * BATCH * NHEADS, 256, 0, stream>>>(
      qb, kb, vb, biasrel, attno);

  gemm64<<<gg, 256, 0, stream>>>(attno, Wo, out, 0);
}

// Round 3
// 201.577 us; speedup vs baseline: 6.5400x; 1.9464x over previous
//
#include <hip/hip_runtime.h>
#include <hip/hip_bf16.h>
#include <math.h>

#define HIDDEN 512
#define NHEADS 8
#define HDIM 64
#define SLEN 2048
#define BATCH 4
#define NROWS (BATCH*SLEN)   /* 8192 */
#define RTAB (2*SLEN-1)      /* 4095 */

typedef _Float16 f16;
typedef f16 f16x8 __attribute__((ext_vector_type(8)));
typedef float f32x4 __attribute__((ext_vector_type(4)));
typedef unsigned short u16;
typedef u16 u16x8 __attribute__((ext_vector_type(8)));

// ---------------------------------------------------------------------------
// Kernel 1: relative-position bias biasrel[h][t-s+2047].
// ---------------------------------------------------------------------------
__global__ __launch_bounds__(256) void bias_precompute(
    const float* __restrict__ bias_table, float* __restrict__ biasrel) {
  int i = blockIdx.x * 256 + threadIdx.x;
  if (i >= NHEADS * RTAB) return;
  int h = i / RTAB;
  int idx = i - h * RTAB;
  int rel = idx - (SLEN - 1);
  int ret = rel > 0 ? 16 : 0;
  int a = rel < 0 ? -rel : rel;
  int bidx;
  if (a < 8) {
    bidx = a;
  } else {
    float val = logf((float)a * 0.125f) / logf(16.0f) * 8.0f;
    bidx = 8 + (int)val;
    if (bidx > 15) bidx = 15;
  }
  biasrel[i] = bias_table[(ret + bidx) * NHEADS + h];
}

// ---------------------------------------------------------------------------
// Kernel 2a: x f32 -> f16 (8 elems/thread)
// ---------------------------------------------------------------------------
__global__ __launch_bounds__(256) void conv_x(
    const float* __restrict__ x, u16* __restrict__ xh) {
  int i = blockIdx.x * 256 + threadIdx.x;
  const float4* p = (const float4*)(x + (size_t)i * 8);
  float4 a = p[0], b = p[1];
  u16x8 o;
  f16 t0 = (f16)a.x; o[0] = *(u16*)&t0;
  f16 t1 = (f16)a.y; o[1] = *(u16*)&t1;
  f16 t2 = (f16)a.z; o[2] = *(u16*)&t2;
  f16 t3 = (f16)a.w; o[3] = *(u16*)&t3;
  f16 t4 = (f16)b.x; o[4] = *(u16*)&t4;
  f16 t5 = (f16)b.y; o[5] = *(u16*)&t5;
  f16 t6 = (f16)b.z; o[6] = *(u16*)&t6;
  f16 t7 = (f16)b.w; o[7] = *(u16*)&t7;
  *(u16x8*)(xh + (size_t)i * 8) = o;
}

// ---------------------------------------------------------------------------
// Kernel 2b: weights f32 [k][n] -> f16 transposed [n][k]. blockIdx.y picks W.
// ---------------------------------------------------------------------------
__global__ __launch_bounds__(256) void conv_w(
    const float* __restrict__ Wq, const float* __restrict__ Wk,
    const float* __restrict__ Wv, const float* __restrict__ Wo,
    u16* __restrict__ Wt) {
  const float* W = blockIdx.y == 0 ? Wq : blockIdx.y == 1 ? Wk
                 : blockIdx.y == 2 ? Wv : Wo;
  u16* dst = Wt + (size_t)blockIdx.y * HIDDEN * HIDDEN;
  int t = blockIdx.x * 256 + threadIdx.x;   // 32768 total
  int k = t >> 6, n0 = (t & 63) << 3;
  const float4* p = (const float4*)(W + (size_t)k * HIDDEN + n0);
  float4 a = p[0], b = p[1];
  float vals[8] = {a.x, a.y, a.z, a.w, b.x, b.y, b.z, b.w};
#pragma unroll
  for (int j = 0; j < 8; ++j) {
    f16 hv = (f16)vals[j];
    dst[(size_t)(n0 + j) * HIDDEN + k] = *(u16*)&hv;
  }
}

// ---------------------------------------------------------------------------
// Kernel 3: f16 MFMA GEMM. C[8192,512] = A(f16,[m][k]) @ Wt(f16,[n][k])^T.
// 128x128 tile, 4 waves (2x2 of 64x64), BK=64. LDS pitch 72 u16 (144B):
// staging writes uniform 8-clk, frag reads 2-way (free).
// mode 0: f32 row-major out (W0 only). mode 1: f16 out [B,H,S,D], z picks W,
// out offset z*NROWS*HIDDEN.
// ---------------------------------------------------------------------------
__global__ __launch_bounds__(256) void gemm_mfma(
    const u16* __restrict__ A, const u16* __restrict__ Wt0,
    const u16* __restrict__ Wt1, const u16* __restrict__ Wt2,
    void* __restrict__ O, int mode) {
  __shared__ u16 As[128][72];
  __shared__ u16 Bs[128][72];
  const u16* Wt = blockIdx.z == 0 ? Wt0 : blockIdx.z == 1 ? Wt1 : Wt2;
  const int tid = threadIdx.x;
  const int w = tid >> 6, l = tid & 63;
  const int lr = l & 15, lg = l >> 4;
  const int wr = w >> 1, wc = w & 1;
  const int m0 = blockIdx.x << 7, n0 = blockIdx.y << 7;

  f32x4 acc[4][4] = {};

  for (int k0 = 0; k0 < HIDDEN; k0 += 64) {
    __syncthreads();
#pragma unroll
    for (int e = 0; e < 4; ++e) {
      int c = (e << 8) + tid;
      int row = c >> 3, g = c & 7;
      *(u16x8*)&As[row][g << 3] =
          *(const u16x8*)(A + (size_t)(m0 + row) * HIDDEN + k0 + (g << 3));
      *(u16x8*)&Bs[row][g << 3] =
          *(const u16x8*)(Wt + (size_t)(n0 + row) * HIDDEN + k0 + (g << 3));
    }
    __syncthreads();
#pragma unroll
    for (int kk = 0; kk < 64; kk += 32) {
      f16x8 af[4], bf[4];
#pragma unroll
      for (int mt = 0; mt < 4; ++mt)
        af[mt] = *(const f16x8*)&As[(wr << 6) + (mt << 4) + lr][kk + (lg << 3)];
#pragma unroll
      for (int nt = 0; nt < 4; ++nt)
        bf[nt] = *(const f16x8*)&Bs[(wc << 6) + (nt << 4) + lr][kk + (lg << 3)];
#pragma unroll
      for (int mt = 0; mt < 4; ++mt)
#pragma unroll
        for (int nt = 0; nt < 4; ++nt)
          acc[mt][nt] = __builtin_amdgcn_mfma_f32_16x16x32_f16(
              af[mt], bf[nt], acc[mt][nt], 0, 0, 0);
    }
  }

  // C/D layout: col = lr, row = lg*4 + r
  if (mode == 0) {
    float* Of = (float*)O;
#pragma unroll
    for (int mt = 0; mt < 4; ++mt)
#pragma unroll
      for (int nt = 0; nt < 4; ++nt)
#pragma unroll
        for (int r = 0; r < 4; ++r) {
          int m = m0 + (wr << 6) + (mt << 4) + (lg << 2) + r;
          int n = n0 + (wc << 6) + (nt << 4) + lr;
          Of[(size_t)m * HIDDEN + n] = acc[mt][nt][r];
        }
  } else {
    u16* O16 = (u16*)O + (size_t)blockIdx.z * NROWS * HIDDEN;
#pragma unroll
    for (int mt = 0; mt < 4; ++mt)
#pragma unroll
      for (int nt = 0; nt < 4; ++nt)
#pragma unroll
        for (int r = 0; r < 4; ++r) {
          int m = m0 + (wr << 6) + (mt << 4) + (lg << 2) + r;
          int n = n0 + (wc << 6) + (nt << 4) + lr;
          int b = m >> 11, s = m & (SLEN - 1);
          int h = n >> 6, d = n & 63;
          f16 hv = (f16)acc[mt][nt][r];
          O16[(((size_t)b * NHEADS + h) * SLEN + s) * HDIM + d] = *(u16*)&hv;
        }
  }
}

// ---------------------------------------------------------------------------
// Kernel 4: MFMA flash attention (as round 1), epilogue now writes f16.
// ---------------------------------------------------------------------------
__global__ __launch_bounds__(256) void flash_attn_mfma(
    const u16* __restrict__ qg, const u16* __restrict__ kg,
    const u16* __restrict__ vg, const float* __restrict__ biasrel,
    u16* __restrict__ attn_out) {
  __shared__ u16 Ks[64][72];
  __shared__ u16 Vt[64][72];
  __shared__ u16 Pb[4][16][72];

  const int tid = threadIdx.x;
  const int w = tid >> 6, l = tid & 63;
  const int lr = l & 15, lg = l >> 4;

  int bid = blockIdx.x;
  int xcd = bid & 7, idx = bid >> 3;
  int bh = (xcd << 2) + (idx >> 5);
  int bx = idx & 31;
  int h = bh & 7, b = bh >> 3;
  int q0 = bx << 6;

  const u16* qp = qg + (size_t)bh * (SLEN * HDIM);
  const u16* kp = kg + (size_t)bh * (SLEN * HDIM);
  const u16* vp = vg + (size_t)bh * (SLEN * HDIM);

  const u16* qrow = qp + (size_t)(q0 + (w << 4) + lr) * HDIM + (lg << 3);
  f16x8 aq0 = *(const f16x8*)(qrow);
  f16x8 aq1 = *(const f16x8*)(qrow + 32);

  const float* bb = biasrel + h * RTAB + (SLEN - 1) + lr - (q0 + (w << 4) + (lg << 2));

  f32x4 acc[4] = {};
  float m_run[4], l_run[4];
#pragma unroll
  for (int r = 0; r < 4; ++r) { m_run[r] = -3.0e38f; l_run[r] = 0.f; }

  for (int t0 = 0; t0 < SLEN; t0 += 64) {
    float bias[4][4];
#pragma unroll
    for (int ct = 0; ct < 4; ++ct)
#pragma unroll
      for (int r = 0; r < 4; ++r) bias[ct][r] = bb[t0 + (ct << 4) - r];

    __syncthreads();
#pragma unroll
    for (int e = 0; e < 2; ++e) {
      int c = tid + (e << 8);
      int row = c >> 3, c8 = c & 7;
      *(float4*)&Ks[row][c8 << 3] = *(const float4*)(kp + (size_t)(t0 + row) * HDIM + (c8 << 3));
    }
#pragma unroll
    for (int e = 0; e < 2; ++e) {
      int c = tid + (e << 8);
      int kr = c & 63, d0 = (c >> 6) << 3;
      u16x8 vv = *(const u16x8*)(vp + (size_t)(t0 + kr) * HDIM + d0);
#pragma unroll
      for (int j = 0; j < 8; ++j) Vt[d0 + j][kr] = vv[j];
    }
    __syncthreads();

    f32x4 sc[4] = {};
#pragma unroll
    for (int ct = 0; ct < 4; ++ct) {
      sc[ct] = __builtin_amdgcn_mfma_f32_16x16x32_f16(
          aq0, *(const f16x8*)&Ks[(ct << 4) + lr][lg << 3], sc[ct], 0, 0, 0);
      sc[ct] = __builtin_amdgcn_mfma_f32_16x16x32_f16(
          aq1, *(const f16x8*)&Ks[(ct << 4) + lr][32 + (lg << 3)], sc[ct], 0, 0, 0);
    }

    float alpha[4];
#pragma unroll
    for (int r = 0; r < 4; ++r) {
      float mx = -3.0e38f;
#pragma unroll
      for (int ct = 0; ct < 4; ++ct) {
        float sv = sc[ct][r] * 0.125f + bias[ct][r];
        sc[ct][r] = sv;
        mx = fmaxf(mx, sv);
      }
      mx = fmaxf(mx, __shfl_xor(mx, 1, 64));
      mx = fmaxf(mx, __shfl_xor(mx, 2, 64));
      mx = fmaxf(mx, __shfl_xor(mx, 4, 64));
      mx = fmaxf(mx, __shfl_xor(mx, 8, 64));
      float mnew = fmaxf(m_run[r], mx);
      alpha[r] = __expf(m_run[r] - mnew);
      m_run[r] = mnew;
      float rs = 0.f;
#pragma unroll
      for (int ct = 0; ct < 4; ++ct) {
        float pe = __expf(sc[ct][r] - mnew);
        sc[ct][r] = pe;
        rs += pe;
      }
      rs += __shfl_xor(rs, 1, 64);
      rs += __shfl_xor(rs, 2, 64);
      rs += __shfl_xor(rs, 4, 64);
      rs += __shfl_xor(rs, 8, 64);
      l_run[r] = l_run[r] * alpha[r] + rs;
    }

#pragma unroll
    for (int ct = 0; ct < 4; ++ct)
#pragma unroll
      for (int r = 0; r < 4; ++r) {
        f16 hp = (f16)sc[ct][r];
        Pb[w][(lg << 2) + r][(ct << 4) + lr] = *(u16*)&hp;
      }

#pragma unroll
    for (int dt = 0; dt < 4; ++dt)
#pragma unroll
      for (int r = 0; r < 4; ++r) acc[dt][r] *= alpha[r];

    f16x8 pa0 = *(const f16x8*)&Pb[w][lr][lg << 3];
    f16x8 pa1 = *(const f16x8*)&Pb[w][lr][32 + (lg << 3)];
#pragma unroll
    for (int dt = 0; dt < 4; ++dt) {
      acc[dt] = __builtin_amdgcn_mfma_f32_16x16x32_f16(
          pa0, *(const f16x8*)&Vt[(dt << 4) + lr][lg << 3], acc[dt], 0, 0, 0);
      acc[dt] = __builtin_amdgcn_mfma_f32_16x16x32_f16(
          pa1, *(const f16x8*)&Vt[(dt << 4) + lr][32 + (lg << 3)], acc[dt], 0, 0, 0);
    }
  }

  u16* op = attn_out + ((size_t)(b * SLEN) + q0 + (w << 4)) * HIDDEN + (h << 6);
#pragma unroll
  for (int r = 0; r < 4; ++r) {
    float inv = 1.f / l_run[r];
#pragma unroll
    for (int dt = 0; dt < 4; ++dt) {
      f16 hv = (f16)(acc[dt][r] * inv);
      op[(size_t)((lg << 2) + r) * HIDDEN + (dt << 4) + lr] = *(u16*)&hv;
    }
  }
}

// ---------------------------------------------------------------------------
extern "C" void kernel_launch(void* const* d_in, const int* in_sizes, int n_in,
                              void* d_out, int out_size, void* d_ws, size_t ws_size,
                              hipStream_t stream) {
  const float* x          = (const float*)d_in[0];
  const float* Wq         = (const float*)d_in[1];
  const float* Wk         = (const float*)d_in[2];
  const float* Wv         = (const float*)d_in[3];
  const float* Wo         = (const float*)d_in[4];
  const float* bias_table = (const float*)d_in[5];
  float* out = (float*)d_out;

  u16* xh   = (u16*)d_ws;                                  // 8 MB
  u16* wt   = xh + (size_t)NROWS * HIDDEN;                 // 2 MB (4 weights)
  u16* qkv  = wt + (size_t)4 * HIDDEN * HIDDEN;            // 24 MB
  u16* attno_h = qkv + (size_t)3 * NROWS * HIDDEN;         // 8 MB
  float* biasrel = (float*)(attno_h + (size_t)NROWS * HIDDEN);

  u16* qb = qkv;
  u16* kb = qkv + (size_t)NROWS * HIDDEN;
  u16* vb = qkv + (size_t)2 * NROWS * HIDDEN;

  bias_precompute<<<(NHEADS * RTAB + 255) / 256, 256, 0, stream>>>(bias_table, biasrel);
  conv_x<<<NROWS * HIDDEN / 8 / 256, 256, 0, stream>>>(x, xh);
  conv_w<<<dim3(HIDDEN * HIDDEN / 8 / 256, 4), 256, 0, stream>>>(Wq, Wk, Wv, Wo, wt);

  u16* wtq = wt;
  u16* wtk = wt + (size_t)HIDDEN * HIDDEN;
  u16* wtv = wt + (size_t)2 * HIDDEN * HIDDEN;
  u16* wto = wt + (size_t)3 * HIDDEN * HIDDEN;

  // Q,K,V in one launch
  gemm_mfma<<<dim3(NROWS / 128, HIDDEN / 128, 3), 256, 0, stream>>>(
      xh, wtq, wtk, wtv, qkv, 1);

  flash_attn_mfma<<<SLEN / 64 * BATCH * NHEADS, 256, 0, stream>>>(
      qb, kb, vb, biasrel, attno_h);

  gemm_mfma<<<dim3(NROWS / 128, HIDDEN / 128, 1), 256, 0, stream>>>(
      attno_h, wto, wto, wto, out, 0);
}

// Round 5
// 155.336 us; speedup vs baseline: 8.4869x; 1.2977x over previous
//
#include <hip/hip_runtime.h>
#include <hip/hip_bf16.h>
#include <math.h>

#define HIDDEN 512
#define NHEADS 8
#define HDIM 64
#define SLEN 2048
#define BATCH 4
#define NROWS (BATCH*SLEN)   /* 8192 */
#define RTAB (2*SLEN-1)      /* 4095 */

typedef _Float16 f16;
typedef f16 f16x8 __attribute__((ext_vector_type(8)));
typedef float f32x4 __attribute__((ext_vector_type(4)));
typedef unsigned short u16;
typedef u16 u16x4 __attribute__((ext_vector_type(4)));
typedef u16 u16x8 __attribute__((ext_vector_type(8)));

// ---------------------------------------------------------------------------
// Kernel 1: relative-position bias biasrel[h][t-s+2047].
// ---------------------------------------------------------------------------
__global__ __launch_bounds__(256) void bias_precompute(
    const float* __restrict__ bias_table, float* __restrict__ biasrel) {
  int i = blockIdx.x * 256 + threadIdx.x;
  if (i >= NHEADS * RTAB) return;
  int h = i / RTAB;
  int idx = i - h * RTAB;
  int rel = idx - (SLEN - 1);
  int ret = rel > 0 ? 16 : 0;
  int a = rel < 0 ? -rel : rel;
  int bidx;
  if (a < 8) {
    bidx = a;
  } else {
    float val = logf((float)a * 0.125f) / logf(16.0f) * 8.0f;
    bidx = 8 + (int)val;
    if (bidx > 15) bidx = 15;
  }
  biasrel[i] = bias_table[(ret + bidx) * NHEADS + h];
}

// ---------------------------------------------------------------------------
// Kernel 2a: x f32 -> f16
// ---------------------------------------------------------------------------
__global__ __launch_bounds__(256) void conv_x(
    const float* __restrict__ x, u16* __restrict__ xh) {
  int i = blockIdx.x * 256 + threadIdx.x;
  const float4* p = (const float4*)(x + (size_t)i * 8);
  float4 a = p[0], b = p[1];
  u16x8 o;
  f16 t0 = (f16)a.x; o[0] = *(u16*)&t0;
  f16 t1 = (f16)a.y; o[1] = *(u16*)&t1;
  f16 t2 = (f16)a.z; o[2] = *(u16*)&t2;
  f16 t3 = (f16)a.w; o[3] = *(u16*)&t3;
  f16 t4 = (f16)b.x; o[4] = *(u16*)&t4;
  f16 t5 = (f16)b.y; o[5] = *(u16*)&t5;
  f16 t6 = (f16)b.z; o[6] = *(u16*)&t6;
  f16 t7 = (f16)b.w; o[7] = *(u16*)&t7;
  *(u16x8*)(xh + (size_t)i * 8) = o;
}

// ---------------------------------------------------------------------------
// Kernel 2b: weights f32 [k][n] -> f16 transposed [n][k].
// ---------------------------------------------------------------------------
__global__ __launch_bounds__(256) void conv_w(
    const float* __restrict__ Wq, const float* __restrict__ Wk,
    const float* __restrict__ Wv, const float* __restrict__ Wo,
    u16* __restrict__ Wt) {
  const float* W = blockIdx.y == 0 ? Wq : blockIdx.y == 1 ? Wk
                 : blockIdx.y == 2 ? Wv : Wo;
  u16* dst = Wt + (size_t)blockIdx.y * HIDDEN * HIDDEN;
  int t = blockIdx.x * 256 + threadIdx.x;
  int k = t >> 6, n0 = (t & 63) << 3;
  const float4* p = (const float4*)(W + (size_t)k * HIDDEN + n0);
  float4 a = p[0], b = p[1];
  float vals[8] = {a.x, a.y, a.z, a.w, b.x, b.y, b.z, b.w};
#pragma unroll
  for (int j = 0; j < 8; ++j) {
    f16 hv = (f16)vals[j];
    dst[(size_t)(n0 + j) * HIDDEN + k] = *(u16*)&hv;
  }
}

// ---------------------------------------------------------------------------
// Kernel 3: f16 MFMA GEMM (unchanged, known-good).
// ---------------------------------------------------------------------------
__global__ __launch_bounds__(256) void gemm_mfma(
    const u16* __restrict__ A, const u16* __restrict__ Wt0,
    const u16* __restrict__ Wt1, const u16* __restrict__ Wt2,
    void* __restrict__ O, int mode) {
  __shared__ u16 As[128][72];
  __shared__ u16 Bs[128][72];
  const u16* Wt = blockIdx.z == 0 ? Wt0 : blockIdx.z == 1 ? Wt1 : Wt2;
  const int tid = threadIdx.x;
  const int w = tid >> 6, l = tid & 63;
  const int lr = l & 15, lg = l >> 4;
  const int wr = w >> 1, wc = w & 1;
  const int m0 = blockIdx.x << 7, n0 = blockIdx.y << 7;

  f32x4 acc[4][4] = {};

  for (int k0 = 0; k0 < HIDDEN; k0 += 64) {
    __syncthreads();
#pragma unroll
    for (int e = 0; e < 4; ++e) {
      int c = (e << 8) + tid;
      int row = c >> 3, g = c & 7;
      *(u16x8*)&As[row][g << 3] =
          *(const u16x8*)(A + (size_t)(m0 + row) * HIDDEN + k0 + (g << 3));
      *(u16x8*)&Bs[row][g << 3] =
          *(const u16x8*)(Wt + (size_t)(n0 + row) * HIDDEN + k0 + (g << 3));
    }
    __syncthreads();
#pragma unroll
    for (int kk = 0; kk < 64; kk += 32) {
      f16x8 af[4], bf[4];
#pragma unroll
      for (int mt = 0; mt < 4; ++mt)
        af[mt] = *(const f16x8*)&As[(wr << 6) + (mt << 4) + lr][kk + (lg << 3)];
#pragma unroll
      for (int nt = 0; nt < 4; ++nt)
        bf[nt] = *(const f16x8*)&Bs[(wc << 6) + (nt << 4) + lr][kk + (lg << 3)];
#pragma unroll
      for (int mt = 0; mt < 4; ++mt)
#pragma unroll
        for (int nt = 0; nt < 4; ++nt)
          acc[mt][nt] = __builtin_amdgcn_mfma_f32_16x16x32_f16(
              af[mt], bf[nt], acc[mt][nt], 0, 0, 0);
    }
  }

  if (mode == 0) {
    float* Of = (float*)O;
#pragma unroll
    for (int mt = 0; mt < 4; ++mt)
#pragma unroll
      for (int nt = 0; nt < 4; ++nt)
#pragma unroll
        for (int r = 0; r < 4; ++r) {
          int m = m0 + (wr << 6) + (mt << 4) + (lg << 2) + r;
          int n = n0 + (wc << 6) + (nt << 4) + lr;
          Of[(size_t)m * HIDDEN + n] = acc[mt][nt][r];
        }
  } else {
    u16* O16 = (u16*)O + (size_t)blockIdx.z * NROWS * HIDDEN;
#pragma unroll
    for (int mt = 0; mt < 4; ++mt)
#pragma unroll
      for (int nt = 0; nt < 4; ++nt)
#pragma unroll
        for (int r = 0; r < 4; ++r) {
          int m = m0 + (wr << 6) + (mt << 4) + (lg << 2) + r;
          int n = n0 + (wc << 6) + (nt << 4) + lr;
          int b = m >> 11, s = m & (SLEN - 1);
          int h = n >> 6, d = n & 63;
          f16 hv = (f16)acc[mt][nt][r];
          O16[(((size_t)b * NHEADS + h) * SLEN + s) * HDIM + d] = *(u16*)&hv;
        }
  }
}

// ---------------------------------------------------------------------------
// Kernel 4: flash attention. Swapped QK^T, in-lane softmax, P in registers.
// 4 waves x 16 q-rows, KVBLK=64.
//  QK: mfma(A=K, B=Q) -> lane(lr,lg) holds S[kv=ct*16+lg*4+r][q=lr]
//  softmax: per-lane row q=lr; reduce over lg via shfl_xor(16,32)
//  PV: mfma(A=P, B=V) with shared k-slot permutation
//      sigma(kb,lg,j) = kb*32 + (j<4 ? lg*4+j : 16+lg*4+j-4)
//      A-frag from sc regs; B-frag = two ds_read_b64 from Vt[d][kv]
// ---------------------------------------------------------------------------
__global__ __launch_bounds__(256) void flash_attn_mfma(
    const u16* __restrict__ qg, const u16* __restrict__ kg,
    const u16* __restrict__ vg, const float* __restrict__ biasrel,
    u16* __restrict__ attn_out) {
  __shared__ u16 Ks[64][72];   // [kv][d]
  __shared__ u16 Vt[64][72];   // [d][kv]

  const int tid = threadIdx.x;
  const int w = tid >> 6, l = tid & 63;
  const int lr = l & 15, lg = l >> 4;

  int bid = blockIdx.x;
  int xcd = bid & 7, idx = bid >> 3;
  int bh = (xcd << 2) + (idx >> 5);
  int bx = idx & 31;
  int h = bh & 7, b = bh >> 3;
  int q0 = bx << 6;

  const u16* qp = qg + (size_t)bh * (SLEN * HDIM);
  const u16* kp = kg + (size_t)bh * (SLEN * HDIM);
  const u16* vp = vg + (size_t)bh * (SLEN * HDIM);

  // Q B-frag: lane holds Q[q=lr][d=kk+lg*8+j]
  const u16* qrow = qp + (size_t)(q0 + (w << 4) + lr) * HDIM + (lg << 3);
  f16x8 aq0 = *(const f16x8*)(qrow);
  f16x8 aq1 = *(const f16x8*)(qrow + 32);

  // bias index = (t0+ct*16+lg*4+r) - (q0+w*16+lr) + 2047
  const float* bb = biasrel + h * RTAB + (SLEN - 1) + (lg << 2) - lr - q0 - (w << 4);

  f32x4 acc[4] = {};
  float m_run = -3.0e38f, l_run = 0.f;

  for (int t0 = 0; t0 < SLEN; t0 += 64) {
    __syncthreads();
    // stage K row-major (b128)
#pragma unroll
    for (int e = 0; e < 2; ++e) {
      int c = tid + (e << 8);
      int row = c >> 3, c8 = (c & 7) << 3;
      *(u16x8*)&Ks[row][c8] = *(const u16x8*)(kp + (size_t)(t0 + row) * HDIM + c8);
    }
    // stage V transposed: Vt[d][kv]
#pragma unroll
    for (int e = 0; e < 2; ++e) {
      int c = tid + (e << 8);
      int kr = c & 63, d0 = (c >> 6) << 3;
      u16x8 vv = *(const u16x8*)(vp + (size_t)(t0 + kr) * HDIM + d0);
#pragma unroll
      for (int j = 0; j < 8; ++j) Vt[d0 + j][kr] = vv[j];
    }
    __syncthreads();

    // S^T = K Q^T
    f32x4 sc[4] = {};
#pragma unroll
    for (int ct = 0; ct < 4; ++ct) {
      sc[ct] = __builtin_amdgcn_mfma_f32_16x16x32_f16(
          *(const f16x8*)&Ks[(ct << 4) + lr][lg << 3], aq0, sc[ct], 0, 0, 0);
      sc[ct] = __builtin_amdgcn_mfma_f32_16x16x32_f16(
          *(const f16x8*)&Ks[(ct << 4) + lr][32 + (lg << 3)], aq1, sc[ct], 0, 0, 0);
    }

    // bias
    float bias_v[4][4];
#pragma unroll
    for (int ct = 0; ct < 4; ++ct)
#pragma unroll
      for (int r = 0; r < 4; ++r)
        bias_v[ct][r] = bb[t0 + (ct << 4) + r];

    // online softmax for this lane's row q=lr
    float mx = -3.0e38f;
#pragma unroll
    for (int ct = 0; ct < 4; ++ct)
#pragma unroll
      for (int r = 0; r < 4; ++r) {
        float sv = sc[ct][r] * 0.125f + bias_v[ct][r];
        sc[ct][r] = sv;
        mx = fmaxf(mx, sv);
      }
    mx = fmaxf(mx, __shfl_xor(mx, 16, 64));
    mx = fmaxf(mx, __shfl_xor(mx, 32, 64));
    float mnew = fmaxf(m_run, mx);
    float alpha = __expf(m_run - mnew);
    m_run = mnew;
    float rs = 0.f;
#pragma unroll
    for (int ct = 0; ct < 4; ++ct)
#pragma unroll
      for (int r = 0; r < 4; ++r) {
        float pe = __expf(sc[ct][r] - mnew);
        sc[ct][r] = pe;
        rs += pe;
      }
    rs += __shfl_xor(rs, 16, 64);
    rs += __shfl_xor(rs, 32, 64);
    l_run = l_run * alpha + rs;

    // rescale O: acc row q' = lg*4+r; its alpha lives at lane lr' = q'
    float ar[4];
#pragma unroll
    for (int r = 0; r < 4; ++r) ar[r] = __shfl(alpha, (lg << 2) + r, 16);
#pragma unroll
    for (int dt = 0; dt < 4; ++dt)
#pragma unroll
      for (int r = 0; r < 4; ++r) acc[dt][r] *= ar[r];

    // PV with permuted k-slots
#pragma unroll
    for (int kb = 0; kb < 2; ++kb) {
      u16x8 pau;
#pragma unroll
      for (int j = 0; j < 4; ++j) {
        f16 p0 = (f16)sc[2 * kb][j];
        f16 p1 = (f16)sc[2 * kb + 1][j];
        pau[j] = *(u16*)&p0;
        pau[j + 4] = *(u16*)&p1;
      }
      f16x8 pa = __builtin_bit_cast(f16x8, pau);
#pragma unroll
      for (int dt = 0; dt < 4; ++dt) {
        u16x4 lo = *(const u16x4*)&Vt[(dt << 4) + lr][(kb << 5) + (lg << 2)];
        u16x4 hi = *(const u16x4*)&Vt[(dt << 4) + lr][(kb << 5) + 16 + (lg << 2)];
        u16x8 vbu;
#pragma unroll
        for (int j = 0; j < 4; ++j) { vbu[j] = lo[j]; vbu[j + 4] = hi[j]; }
        f16x8 vbf = __builtin_bit_cast(f16x8, vbu);
        acc[dt] = __builtin_amdgcn_mfma_f32_16x16x32_f16(pa, vbf, acc[dt], 0, 0, 0);
      }
    }
  }

  // epilogue: acc[dt][r] = O[q=lg*4+r][d=dt*16+lr]; l_run lives at lane lr'=q
  float linv[4];
#pragma unroll
  for (int r = 0; r < 4; ++r) linv[r] = 1.f / __shfl(l_run, (lg << 2) + r, 16);
  u16* op = attn_out + ((size_t)(b * SLEN) + q0 + (w << 4)) * HIDDEN + (h << 6);
#pragma unroll
  for (int r = 0; r < 4; ++r)
#pragma unroll
    for (int dt = 0; dt < 4; ++dt) {
      f16 hv = (f16)(acc[dt][r] * linv[r]);
      op[(size_t)((lg << 2) + r) * HIDDEN + (dt << 4) + lr] = *(u16*)&hv;
    }
}

// ---------------------------------------------------------------------------
extern "C" void kernel_launch(void* const* d_in, const int* in_sizes, int n_in,
                              void* d_out, int out_size, void* d_ws, size_t ws_size,
                              hipStream_t stream) {
  const float* x          = (const float*)d_in[0];
  const float* Wq         = (const float*)d_in[1];
  const float* Wk         = (const float*)d_in[2];
  const float* Wv         = (const float*)d_in[3];
  const float* Wo         = (const float*)d_in[4];
  const float* bias_table = (const float*)d_in[5];
  float* out = (float*)d_out;

  u16* xh   = (u16*)d_ws;
  u16* wt   = xh + (size_t)NROWS * HIDDEN;
  u16* qkv  = wt + (size_t)4 * HIDDEN * HIDDEN;
  u16* attno_h = qkv + (size_t)3 * NROWS * HIDDEN;
  float* biasrel = (float*)(attno_h + (size_t)NROWS * HIDDEN);

  u16* qb = qkv;
  u16* kb = qkv + (size_t)NROWS * HIDDEN;
  u16* vb = qkv + (size_t)2 * NROWS * HIDDEN;

  bias_precompute<<<(NHEADS * RTAB + 255) / 256, 256, 0, stream>>>(bias_table, biasrel);
  conv_x<<<NROWS * HIDDEN / 8 / 256, 256, 0, stream>>>(x, xh);
  conv_w<<<dim3(HIDDEN * HIDDEN / 8 / 256, 4), 256, 0, stream>>>(Wq, Wk, Wv, Wo, wt);

  u16* wtq = wt;
  u16* wtk = wt + (size_t)HIDDEN * HIDDEN;
  u16* wtv = wt + (size_t)2 * HIDDEN * HIDDEN;
  u16* wto = wt + (size_t)3 * HIDDEN * HIDDEN;

  gemm_mfma<<<dim3(NROWS / 128, HIDDEN / 128, 3), 256, 0, stream>>>(
      xh, wtq, wtk, wtv, qkv, 1);

  flash_attn_mfma<<<SLEN / 64 * BATCH * NHEADS, 256, 0, stream>>>(
      qb, kb, vb, biasrel, attno_h);

  gemm_mfma<<<dim3(NROWS / 128, HIDDEN / 128, 1), 256, 0, stream>>>(
      attno_h, wto, wto, wto, out, 0);
}

// Round 6
// 140.774 us; speedup vs baseline: 9.3647x; 1.1034x over previous
//
#include <hip/hip_runtime.h>
#include <hip/hip_bf16.h>
#include <math.h>

#define HIDDEN 512
#define NHEADS 8
#define HDIM 64
#define SLEN 2048
#define BATCH 4
#define NROWS (BATCH*SLEN)   /* 8192 */
#define RTAB (2*SLEN-1)      /* 4095 */
#define LOG2E 1.44269504088896340736f
#define SCALE_L2E (0.125f * LOG2E)

typedef _Float16 f16;
typedef f16 f16x8 __attribute__((ext_vector_type(8)));
typedef float f32x4 __attribute__((ext_vector_type(4)));
typedef unsigned short u16;
typedef u16 u16x4 __attribute__((ext_vector_type(4)));
typedef u16 u16x8 __attribute__((ext_vector_type(8)));

// ---------------------------------------------------------------------------
// Kernel 1: relative-position bias biasrel[h][t-s+2047], pre-scaled by log2e.
// ---------------------------------------------------------------------------
__global__ __launch_bounds__(256) void bias_precompute(
    const float* __restrict__ bias_table, float* __restrict__ biasrel) {
  int i = blockIdx.x * 256 + threadIdx.x;
  if (i >= NHEADS * RTAB) return;
  int h = i / RTAB;
  int idx = i - h * RTAB;
  int rel = idx - (SLEN - 1);
  int ret = rel > 0 ? 16 : 0;
  int a = rel < 0 ? -rel : rel;
  int bidx;
  if (a < 8) {
    bidx = a;
  } else {
    float val = logf((float)a * 0.125f) / logf(16.0f) * 8.0f;
    bidx = 8 + (int)val;
    if (bidx > 15) bidx = 15;
  }
  biasrel[i] = bias_table[(ret + bidx) * NHEADS + h] * LOG2E;
}

// ---------------------------------------------------------------------------
// Kernel 2a: x f32 -> f16
// ---------------------------------------------------------------------------
__global__ __launch_bounds__(256) void conv_x(
    const float* __restrict__ x, u16* __restrict__ xh) {
  int i = blockIdx.x * 256 + threadIdx.x;
  const float4* p = (const float4*)(x + (size_t)i * 8);
  float4 a = p[0], b = p[1];
  u16x8 o;
  f16 t0 = (f16)a.x; o[0] = *(u16*)&t0;
  f16 t1 = (f16)a.y; o[1] = *(u16*)&t1;
  f16 t2 = (f16)a.z; o[2] = *(u16*)&t2;
  f16 t3 = (f16)a.w; o[3] = *(u16*)&t3;
  f16 t4 = (f16)b.x; o[4] = *(u16*)&t4;
  f16 t5 = (f16)b.y; o[5] = *(u16*)&t5;
  f16 t6 = (f16)b.z; o[6] = *(u16*)&t6;
  f16 t7 = (f16)b.w; o[7] = *(u16*)&t7;
  *(u16x8*)(xh + (size_t)i * 8) = o;
}

// ---------------------------------------------------------------------------
// Kernel 2b: weights f32 [k][n] -> f16 transposed [n][k].
// ---------------------------------------------------------------------------
__global__ __launch_bounds__(256) void conv_w(
    const float* __restrict__ Wq, const float* __restrict__ Wk,
    const float* __restrict__ Wv, const float* __restrict__ Wo,
    u16* __restrict__ Wt) {
  const float* W = blockIdx.y == 0 ? Wq : blockIdx.y == 1 ? Wk
                 : blockIdx.y == 2 ? Wv : Wo;
  u16* dst = Wt + (size_t)blockIdx.y * HIDDEN * HIDDEN;
  int t = blockIdx.x * 256 + threadIdx.x;
  int k = t >> 6, n0 = (t & 63) << 3;
  const float4* p = (const float4*)(W + (size_t)k * HIDDEN + n0);
  float4 a = p[0], b = p[1];
  float vals[8] = {a.x, a.y, a.z, a.w, b.x, b.y, b.z, b.w};
#pragma unroll
  for (int j = 0; j < 8; ++j) {
    f16 hv = (f16)vals[j];
    dst[(size_t)(n0 + j) * HIDDEN + k] = *(u16*)&hv;
  }
}

// ---------------------------------------------------------------------------
// Kernel 3: f16 MFMA GEMM (unchanged, known-good).
// ---------------------------------------------------------------------------
__global__ __launch_bounds__(256) void gemm_mfma(
    const u16* __restrict__ A, const u16* __restrict__ Wt0,
    const u16* __restrict__ Wt1, const u16* __restrict__ Wt2,
    void* __restrict__ O, int mode) {
  __shared__ u16 As[128][72];
  __shared__ u16 Bs[128][72];
  const u16* Wt = blockIdx.z == 0 ? Wt0 : blockIdx.z == 1 ? Wt1 : Wt2;
  const int tid = threadIdx.x;
  const int w = tid >> 6, l = tid & 63;
  const int lr = l & 15, lg = l >> 4;
  const int wr = w >> 1, wc = w & 1;
  const int m0 = blockIdx.x << 7, n0 = blockIdx.y << 7;

  f32x4 acc[4][4] = {};

  for (int k0 = 0; k0 < HIDDEN; k0 += 64) {
    __syncthreads();
#pragma unroll
    for (int e = 0; e < 4; ++e) {
      int c = (e << 8) + tid;
      int row = c >> 3, g = c & 7;
      *(u16x8*)&As[row][g << 3] =
          *(const u16x8*)(A + (size_t)(m0 + row) * HIDDEN + k0 + (g << 3));
      *(u16x8*)&Bs[row][g << 3] =
          *(const u16x8*)(Wt + (size_t)(n0 + row) * HIDDEN + k0 + (g << 3));
    }
    __syncthreads();
#pragma unroll
    for (int kk = 0; kk < 64; kk += 32) {
      f16x8 af[4], bf[4];
#pragma unroll
      for (int mt = 0; mt < 4; ++mt)
        af[mt] = *(const f16x8*)&As[(wr << 6) + (mt << 4) + lr][kk + (lg << 3)];
#pragma unroll
      for (int nt = 0; nt < 4; ++nt)
        bf[nt] = *(const f16x8*)&Bs[(wc << 6) + (nt << 4) + lr][kk + (lg << 3)];
#pragma unroll
      for (int mt = 0; mt < 4; ++mt)
#pragma unroll
        for (int nt = 0; nt < 4; ++nt)
          acc[mt][nt] = __builtin_amdgcn_mfma_f32_16x16x32_f16(
              af[mt], bf[nt], acc[mt][nt], 0, 0, 0);
    }
  }

  if (mode == 0) {
    float* Of = (float*)O;
#pragma unroll
    for (int mt = 0; mt < 4; ++mt)
#pragma unroll
      for (int nt = 0; nt < 4; ++nt)
#pragma unroll
        for (int r = 0; r < 4; ++r) {
          int m = m0 + (wr << 6) + (mt << 4) + (lg << 2) + r;
          int n = n0 + (wc << 6) + (nt << 4) + lr;
          Of[(size_t)m * HIDDEN + n] = acc[mt][nt][r];
        }
  } else {
    u16* O16 = (u16*)O + (size_t)blockIdx.z * NROWS * HIDDEN;
#pragma unroll
    for (int mt = 0; mt < 4; ++mt)
#pragma unroll
      for (int nt = 0; nt < 4; ++nt)
#pragma unroll
        for (int r = 0; r < 4; ++r) {
          int m = m0 + (wr << 6) + (mt << 4) + (lg << 2) + r;
          int n = n0 + (wc << 6) + (nt << 4) + lr;
          int b = m >> 11, s = m & (SLEN - 1);
          int h = n >> 6, d = n & 63;
          f16 hv = (f16)acc[mt][nt][r];
          O16[(((size_t)b * NHEADS + h) * SLEN + s) * HDIM + d] = *(u16*)&hv;
        }
  }
}

// ---------------------------------------------------------------------------
// Kernel 4: flash attention. Swapped QK^T, in-lane softmax (log2 domain),
// P in registers. 4 waves x 2 subtiles x 16 q-rows = 128 q-rows/block, KVBLK=64.
//  QK: mfma(A=K, B=Q) -> lane(lr,lg) holds S[kv=ct*16+lg*4+r][q=lr]
//  PV: mfma(A=P, B=V), shared k-slot permutation
//      sigma(kb,lg,j) = kb*32 + (j<4 ? lg*4+j : 16+lg*4+(j-4))
//  K-frags/V-frags/staging amortized over both subtiles.
// ---------------------------------------------------------------------------
__global__ __launch_bounds__(256) void flash_attn_mfma(
    const u16* __restrict__ qg, const u16* __restrict__ kg,
    const u16* __restrict__ vg, const float* __restrict__ biasrel,
    u16* __restrict__ attn_out) {
  __shared__ u16 Ks[64][72];   // [kv][d]
  __shared__ u16 Vt[64][72];   // [d][kv]

  const int tid = threadIdx.x;
  const int w = tid >> 6, l = tid & 63;
  const int lr = l & 15, lg = l >> 4;

  // grid 512 = 32 bh x 16 qtiles; XCD swizzle: 4 bh per XCD (K/V L2-resident)
  int bid = blockIdx.x;
  int xcd = bid & 7, idx = bid >> 3;
  int bh = (xcd << 2) + (idx >> 4);
  int bx = idx & 15;
  int h = bh & 7, b = bh >> 3;
  int q0 = bx << 7;            // 128 q-rows per block

  const u16* qp = qg + (size_t)bh * (SLEN * HDIM);
  const u16* kp = kg + (size_t)bh * (SLEN * HDIM);
  const u16* vp = vg + (size_t)bh * (SLEN * HDIM);

  // Q B-frags for both subtiles: lane holds Q[q=lr][d=kk+lg*8+j]
  f16x8 aq[2][2];
#pragma unroll
  for (int sub = 0; sub < 2; ++sub) {
    const u16* qrow = qp + (size_t)(q0 + (w << 5) + (sub << 4) + lr) * HDIM + (lg << 3);
    aq[sub][0] = *(const f16x8*)(qrow);
    aq[sub][1] = *(const f16x8*)(qrow + 32);
  }

  // bias index = (t0+ct*16+lg*4+r) - (q0+w*32+sub*16+lr) + 2047
  const float* bb = biasrel + h * RTAB + (SLEN - 1) + (lg << 2) - lr - q0 - (w << 5);

  f32x4 acc[2][4] = {};
  float m_run[2] = {-3.0e38f, -3.0e38f};
  float l_run[2] = {0.f, 0.f};

  for (int t0 = 0; t0 < SLEN; t0 += 64) {
    __syncthreads();
    // stage K row-major (b128)
#pragma unroll
    for (int e = 0; e < 2; ++e) {
      int c = tid + (e << 8);
      int row = c >> 3, c8 = (c & 7) << 3;
      *(u16x8*)&Ks[row][c8] = *(const u16x8*)(kp + (size_t)(t0 + row) * HDIM + c8);
    }
    // stage V transposed: Vt[d][kv]
#pragma unroll
    for (int e = 0; e < 2; ++e) {
      int c = tid + (e << 8);
      int kr = c & 63, d0 = (c >> 6) << 3;
      u16x8 vv = *(const u16x8*)(vp + (size_t)(t0 + kr) * HDIM + d0);
#pragma unroll
      for (int j = 0; j < 8; ++j) Vt[d0 + j][kr] = vv[j];
    }
    __syncthreads();

    // K A-frags, shared by both subtiles
    f16x8 kf[4][2];
#pragma unroll
    for (int ct = 0; ct < 4; ++ct) {
      kf[ct][0] = *(const f16x8*)&Ks[(ct << 4) + lr][lg << 3];
      kf[ct][1] = *(const f16x8*)&Ks[(ct << 4) + lr][32 + (lg << 3)];
    }

    // S^T = K Q^T for both subtiles
    f32x4 sc[2][4] = {};
#pragma unroll
    for (int sub = 0; sub < 2; ++sub)
#pragma unroll
      for (int ct = 0; ct < 4; ++ct) {
        sc[sub][ct] = __builtin_amdgcn_mfma_f32_16x16x32_f16(
            kf[ct][0], aq[sub][0], sc[sub][ct], 0, 0, 0);
        sc[sub][ct] = __builtin_amdgcn_mfma_f32_16x16x32_f16(
            kf[ct][1], aq[sub][1], sc[sub][ct], 0, 0, 0);
      }

    // online softmax (log2 domain) per subtile; lane owns row q=lr
    float alpha[2];
    int nochg = 1;
#pragma unroll
    for (int sub = 0; sub < 2; ++sub) {
      float mx = -3.0e38f;
#pragma unroll
      for (int ct = 0; ct < 4; ++ct)
#pragma unroll
        for (int r = 0; r < 4; ++r) {
          float sv = sc[sub][ct][r] * SCALE_L2E + bb[t0 + (ct << 4) + r - (sub << 4)];
          sc[sub][ct][r] = sv;
          mx = fmaxf(mx, sv);
        }
      mx = fmaxf(mx, __shfl_xor(mx, 16, 64));
      mx = fmaxf(mx, __shfl_xor(mx, 32, 64));
      float mnew = fmaxf(m_run[sub], mx);
      alpha[sub] = __builtin_amdgcn_exp2f(m_run[sub] - mnew);
      nochg &= (mnew == m_run[sub]);
      m_run[sub] = mnew;
      float rs = 0.f;
#pragma unroll
      for (int ct = 0; ct < 4; ++ct)
#pragma unroll
        for (int r = 0; r < 4; ++r) {
          float pe = __builtin_amdgcn_exp2f(sc[sub][ct][r] - mnew);
          sc[sub][ct][r] = pe;
          rs += pe;
        }
      rs += __shfl_xor(rs, 16, 64);
      rs += __shfl_xor(rs, 32, 64);
      l_run[sub] = l_run[sub] * alpha[sub] + rs;
    }

    // rescale O (skip when exactly identity for the whole wave)
    if (!__all(nochg)) {
#pragma unroll
      for (int sub = 0; sub < 2; ++sub) {
        float ar[4];
#pragma unroll
        for (int r = 0; r < 4; ++r) ar[r] = __shfl(alpha[sub], (lg << 2) + r, 16);
#pragma unroll
        for (int dt = 0; dt < 4; ++dt)
#pragma unroll
          for (int r = 0; r < 4; ++r) acc[sub][dt][r] *= ar[r];
      }
    }

    // V B-frags, shared by both subtiles
    f16x8 vf[2][4];
#pragma unroll
    for (int kb = 0; kb < 2; ++kb)
#pragma unroll
      for (int dt = 0; dt < 4; ++dt) {
        u16x4 lo = *(const u16x4*)&Vt[(dt << 4) + lr][(kb << 5) + (lg << 2)];
        u16x4 hi = *(const u16x4*)&Vt[(dt << 4) + lr][(kb << 5) + 16 + (lg << 2)];
        u16x8 vbu;
#pragma unroll
        for (int j = 0; j < 4; ++j) { vbu[j] = lo[j]; vbu[j + 4] = hi[j]; }
        vf[kb][dt] = __builtin_bit_cast(f16x8, vbu);
      }

    // PV with permuted k-slots
#pragma unroll
    for (int sub = 0; sub < 2; ++sub)
#pragma unroll
      for (int kb = 0; kb < 2; ++kb) {
        u16x8 pau;
#pragma unroll
        for (int j = 0; j < 4; ++j) {
          f16 p0 = (f16)sc[sub][2 * kb][j];
          f16 p1 = (f16)sc[sub][2 * kb + 1][j];
          pau[j] = *(u16*)&p0;
          pau[j + 4] = *(u16*)&p1;
        }
        f16x8 pa = __builtin_bit_cast(f16x8, pau);
#pragma unroll
        for (int dt = 0; dt < 4; ++dt)
          acc[sub][dt] = __builtin_amdgcn_mfma_f32_16x16x32_f16(
              pa, vf[kb][dt], acc[sub][dt], 0, 0, 0);
      }
  }

  // epilogue: acc[sub][dt][r] = O[q=lg*4+r][d=dt*16+lr]; l_run at lane lr'=q
#pragma unroll
  for (int sub = 0; sub < 2; ++sub) {
    float linv[4];
#pragma unroll
    for (int r = 0; r < 4; ++r) linv[r] = 1.f / __shfl(l_run[sub], (lg << 2) + r, 16);
    u16* op = attn_out +
              ((size_t)(b * SLEN) + q0 + (w << 5) + (sub << 4)) * HIDDEN + (h << 6);
#pragma unroll
    for (int r = 0; r < 4; ++r)
#pragma unroll
      for (int dt = 0; dt < 4; ++dt) {
        f16 hv = (f16)(acc[sub][dt][r] * linv[r]);
        op[(size_t)((lg << 2) + r) * HIDDEN + (dt << 4) + lr] = *(u16*)&hv;
      }
  }
}

// ---------------------------------------------------------------------------
extern "C" void kernel_launch(void* const* d_in, const int* in_sizes, int n_in,
                              void* d_out, int out_size, void* d_ws, size_t ws_size,
                              hipStream_t stream) {
  const float* x          = (const float*)d_in[0];
  const float* Wq         = (const float*)d_in[1];
  const float* Wk         = (const float*)d_in[2];
  const float* Wv         = (const float*)d_in[3];
  const float* Wo         = (const float*)d_in[4];
  const float* bias_table = (const float*)d_in[5];
  float* out = (float*)d_out;

  u16* xh   = (u16*)d_ws;
  u16* wt   = xh + (size_t)NROWS * HIDDEN;
  u16* qkv  = wt + (size_t)4 * HIDDEN * HIDDEN;
  u16* attno_h = qkv + (size_t)3 * NROWS * HIDDEN;
  float* biasrel = (float*)(attno_h + (size_t)NROWS * HIDDEN);

  u16* qb = qkv;
  u16* kb = qkv + (size_t)NROWS * HIDDEN;
  u16* vb = qkv + (size_t)2 * NROWS * HIDDEN;

  bias_precompute<<<(NHEADS * RTAB + 255) / 256, 256, 0, stream>>>(bias_table, biasrel);
  conv_x<<<NROWS * HIDDEN / 8 / 256, 256, 0, stream>>>(x, xh);
  conv_w<<<dim3(HIDDEN * HIDDEN / 8 / 256, 4), 256, 0, stream>>>(Wq, Wk, Wv, Wo, wt);

  u16* wtq = wt;
  u16* wtk = wt + (size_t)HIDDEN * HIDDEN;
  u16* wtv = wt + (size_t)2 * HIDDEN * HIDDEN;
  u16* wto = wt + (size_t)3 * HIDDEN * HIDDEN;

  gemm_mfma<<<dim3(NROWS / 128, HIDDEN / 128, 3), 256, 0, stream>>>(
      xh, wtq, wtk, wtv, qkv, 1);

  flash_attn_mfma<<<SLEN / 128 * BATCH * NHEADS, 256, 0, stream>>>(
      qb, kb, vb, biasrel, attno_h);

  gemm_mfma<<<dim3(NROWS / 128, HIDDEN / 128, 1), 256, 0, stream>>>(
      attno_h, wto, wto, wto, out, 0);
}